// Round 4
// baseline (317.481 us; speedup 1.0000x reference)
//
#include <hip/hip_runtime.h>
#include <hip/hip_bf16.h>
#include <cstdint>

// ---------------------------------------------------------------------------
// MLPDecoder: logit[e] = relu([zu, zv, |zu-zv|] @ W1 + b1) @ W2 + b2
// Round-4:
//   feat@W1 = zu@W1a + zv@W1b + |zu-zv|@W1c
//   K0: pack W1 -> MFMA B-frag order (bf16)
//   K1: precompute U[node] = [bf16(z) | (z@W1a)]  (512B rows)
//                  Pbv[node] = (z@W1b)            (256B rows)
//       P stores coalesced via LDS transpose stage.
//   K2: edge kernel, E_TILE=32, ~18KB LDS -> 8 blocks/CU (100% occ target).
//       u-gather = ONE contiguous 512B region; v-gather = 256B + 256B.
//       K=128 MFMA for |zu-zv|@W1c; H=Pa+Pb added pre-relu; W2 dot fused.
// ---------------------------------------------------------------------------

typedef __bf16 bf16_t;
typedef __bf16 bf16x8 __attribute__((ext_vector_type(8)));
typedef float  floatx4 __attribute__((ext_vector_type(4)));

#define DIM 128
#define LDA 136              // rows 272B = 17*16 (16B-aligned); bank-OK
#define LDP 264              // Pstage rows 528B = 33*16
#define NB_TILE 64
#define ET 32                // edges per block (kernel B)
#define N_KSTEP 12
#define N_NTILE 8

__device__ inline float bflo(unsigned w) { return __uint_as_float(w << 16); }
__device__ inline float bfhi(unsigned w) { return __uint_as_float(w & 0xffff0000u); }
__device__ inline float bf2f(unsigned short u) { return __uint_as_float(((unsigned)u) << 16); }

// ===========================================================================
// K0: pack W1 [384,128] f32 -> bf16 MFMA B-frag order.
// frag f = ks*8+nt; lane l holds B[k=ks*32+(l>>4)*8+j][n=nt*16+(l&15)], j=0..7
// ===========================================================================
__global__ void pack_w1_kernel(const float* __restrict__ W1, bf16_t* __restrict__ Wp) {
    int f = blockIdx.x * 256 + threadIdx.x;
    if (f >= N_KSTEP * N_NTILE * 64) return;
    int lane = f & 63;
    int nt   = (f >> 6) & 7;
    int ks   = f >> 9;
    int n  = nt * 16 + (lane & 15);
    int k0 = ks * 32 + (lane >> 4) * 8;
    bf16x8 o;
#pragma unroll
    for (int j = 0; j < 8; ++j) o[j] = (bf16_t)W1[(k0 + j) * DIM + n];
    reinterpret_cast<bf16x8*>(Wp)[f] = o;
}

// ===========================================================================
// K1: U[node] = [bf16(z[node]) | Pa[node]],  Pbv[node] = Pb[node]
//     where [Pa|Pb] = z @ [W1a|W1b]   (bf16 outputs)
// ===========================================================================
__global__ __launch_bounds__(256)
void precompute_kernel(const float* __restrict__ z,
                       const bf16_t* __restrict__ Wp,
                       bf16_t* __restrict__ U,
                       bf16_t* __restrict__ Pbv,
                       int Nn) {
    __shared__ __align__(16) bf16_t A[NB_TILE * LDA];     // 17408 B
    __shared__ __align__(16) bf16_t Pst[NB_TILE * LDP];   // 33792 B
    const int tid = threadIdx.x;
    const int node0 = (int)blockIdx.x * NB_TILE;

    // ---- stage z tile -> bf16 LDS ----
#pragma unroll
    for (int i = 0; i < 4; ++i) {
        int t = i * 256 + tid;
        int m = t >> 4, c = (t & 15) * 8;
        int node = node0 + m;
        int nc = node < Nn ? node : Nn - 1;
        const float4* src = reinterpret_cast<const float4*>(z + (size_t)nc * DIM + c);
        float4 a = src[0], b = src[1];
        bf16x8 o;
        o[0]=(bf16_t)a.x; o[1]=(bf16_t)a.y; o[2]=(bf16_t)a.z; o[3]=(bf16_t)a.w;
        o[4]=(bf16_t)b.x; o[5]=(bf16_t)b.y; o[6]=(bf16_t)b.z; o[7]=(bf16_t)b.w;
        *reinterpret_cast<bf16x8*>(&A[m * LDA + c]) = o;
    }
    __syncthreads();

    const int wave = tid >> 6, lane = tid & 63;
    const int l15 = lane & 15, quad = lane >> 4;
    const bf16x8* WpF = reinterpret_cast<const bf16x8*>(Wp);

    floatx4 acc[4][4];
#pragma unroll
    for (int mt = 0; mt < 4; ++mt)
#pragma unroll
        for (int nt = 0; nt < 4; ++nt) acc[mt][nt] = (floatx4)0.0f;

    // wave w covers output cols np = w*64 .. +63 of the 256-wide [W1a|W1b]
#pragma unroll
    for (int ks = 0; ks < 4; ++ks) {
        bf16x8 bfrag[4];
#pragma unroll
        for (int nt = 0; nt < 4; ++nt) {
            int f = (ks + (wave >> 1) * 4) * 8 + (wave & 1) * 4 + nt;
            bfrag[nt] = WpF[f * 64 + lane];
        }
#pragma unroll
        for (int mt = 0; mt < 4; ++mt) {
            bf16x8 afrag = *reinterpret_cast<const bf16x8*>(
                &A[(mt * 16 + l15) * LDA + ks * 32 + quad * 8]);
#pragma unroll
            for (int nt = 0; nt < 4; ++nt)
                acc[mt][nt] = __builtin_amdgcn_mfma_f32_16x16x32_bf16(
                    afrag, bfrag[nt], acc[mt][nt], 0, 0, 0);
        }
    }

    // ---- transpose-stage acc into Pst (C layout: np col = wave*64+nt*16+l15,
    //      row = mt*16+quad*4+r) ----
#pragma unroll
    for (int mt = 0; mt < 4; ++mt)
#pragma unroll
        for (int r = 0; r < 4; ++r) {
            int row = mt * 16 + quad * 4 + r;
#pragma unroll
            for (int nt = 0; nt < 4; ++nt) {
                int col = wave * 64 + nt * 16 + l15;
                Pst[row * LDP + col] = (bf16_t)acc[mt][nt][r];
            }
        }
    __syncthreads();

    // ---- coalesced global writes: U zb-half, U Pa-half, Pbv ----
#pragma unroll
    for (int i = 0; i < 4; ++i) {
        int t = i * 256 + tid;
        int m = t >> 4, c = (t & 15) * 8;
        int node = node0 + m;
        if (node < Nn) {
            uint4 zb4 = *reinterpret_cast<const uint4*>(&A[m * LDA + c]);
            uint4 pa4 = *reinterpret_cast<const uint4*>(&Pst[m * LDP + c]);
            uint4 pb4 = *reinterpret_cast<const uint4*>(&Pst[m * LDP + DIM + c]);
            *reinterpret_cast<uint4*>(U + (size_t)node * 256 + c)        = zb4;
            *reinterpret_cast<uint4*>(U + (size_t)node * 256 + DIM + c)  = pa4;
            *reinterpret_cast<uint4*>(Pbv + (size_t)node * DIM + c)      = pb4;
        }
    }
}

// ===========================================================================
// K2: edge kernel, 32 edges/block, 8 threads/edge.
//   sub<4:  loads U[u] chunk sub (zu) + U[v] chunk sub (zv) -> A=|zu-zv|
//   sub>=4: loads U[u] chunk sub (Pa) + Pbv[v] chunk sub-4 (Pb) -> H=Pa+Pb
// ===========================================================================
__global__ __launch_bounds__(256, 8)
void edge_kernel(const bf16_t* __restrict__ U,
                 const bf16_t* __restrict__ Pbv,
                 const bf16_t* __restrict__ Wp,
                 const int* __restrict__ ei,
                 const float* __restrict__ b1,
                 const float* __restrict__ W2,
                 const float* __restrict__ b2,
                 float* __restrict__ out, int E) {
    __shared__ __align__(16) bf16_t A[ET * LDA];   // 8704 B
    __shared__ __align__(16) bf16_t H[ET * LDA];   // 8704 B
    __shared__ float red[4][ET];                   // 512 B

    const int tid = threadIdx.x;
    const int ebase = (int)blockIdx.x * ET;
    const int el  = tid >> 3;      // edge 0..31
    const int sub = tid & 7;       // chunk 0..7

    int e = ebase + el; if (e >= E) e = E - 1;
    int u = ei[e], v = ei[E + e];

    // ---- gathers: u-side one 512B region; v-side 256B region ----
    const uint4* pu = reinterpret_cast<const uint4*>(U + (size_t)u * 256 + sub * 32);
    const uint4* pv = (sub < 4)
        ? reinterpret_cast<const uint4*>(U + (size_t)v * 256 + sub * 32)
        : reinterpret_cast<const uint4*>(Pbv + (size_t)v * DIM + (sub - 4) * 32);
    uint4 gu[4], gv[4];
#pragma unroll
    for (int j = 0; j < 4; ++j) gu[j] = pu[j];
#pragma unroll
    for (int j = 0; j < 4; ++j) gv[j] = pv[j];

    const int wave = tid >> 6, lane = tid & 63;
    const int l15 = lane & 15, quad = lane >> 4;

    float b1v[2], w2v[2];
#pragma unroll
    for (int nt = 0; nt < 2; ++nt) {
        int n = (wave * 2 + nt) * 16 + l15;
        b1v[nt] = b1[n];
        w2v[nt] = W2[n];
    }

    // ---- convert + LDS write ----
    if (sub < 4) {
        bf16_t* dst = &A[el * LDA + sub * 32];
#pragma unroll
        for (int j = 0; j < 4; ++j) {
            uint4 a = gu[j], b = gv[j];
            bf16x8 d;
            d[0]=(bf16_t)fabsf(bflo(a.x)-bflo(b.x));
            d[1]=(bf16_t)fabsf(bfhi(a.x)-bfhi(b.x));
            d[2]=(bf16_t)fabsf(bflo(a.y)-bflo(b.y));
            d[3]=(bf16_t)fabsf(bfhi(a.y)-bfhi(b.y));
            d[4]=(bf16_t)fabsf(bflo(a.z)-bflo(b.z));
            d[5]=(bf16_t)fabsf(bfhi(a.z)-bfhi(b.z));
            d[6]=(bf16_t)fabsf(bflo(a.w)-bflo(b.w));
            d[7]=(bf16_t)fabsf(bfhi(a.w)-bfhi(b.w));
            *reinterpret_cast<bf16x8*>(dst + j * 8) = d;
        }
    } else {
        bf16_t* dst = &H[el * LDA + (sub - 4) * 32];
#pragma unroll
        for (int j = 0; j < 4; ++j) {
            uint4 a = gu[j], b = gv[j];
            bf16x8 h;
            h[0]=(bf16_t)(bflo(a.x)+bflo(b.x));
            h[1]=(bf16_t)(bfhi(a.x)+bfhi(b.x));
            h[2]=(bf16_t)(bflo(a.y)+bflo(b.y));
            h[3]=(bf16_t)(bfhi(a.y)+bfhi(b.y));
            h[4]=(bf16_t)(bflo(a.z)+bflo(b.z));
            h[5]=(bf16_t)(bfhi(a.z)+bfhi(b.z));
            h[6]=(bf16_t)(bflo(a.w)+bflo(b.w));
            h[7]=(bf16_t)(bfhi(a.w)+bfhi(b.w));
            *reinterpret_cast<bf16x8*>(dst + j * 8) = h;
        }
    }
    __syncthreads();

    // ---- MFMA: 2 m-tiles x 2 n-tiles per wave, K=128 (W1c = frags ks 8..11)
    floatx4 acc[2][2];
#pragma unroll
    for (int mt = 0; mt < 2; ++mt)
#pragma unroll
        for (int nt = 0; nt < 2; ++nt) acc[mt][nt] = (floatx4)0.0f;

    const bf16x8* WpF = reinterpret_cast<const bf16x8*>(Wp);
#pragma unroll
    for (int ks = 0; ks < 4; ++ks) {
        bf16x8 bfrag[2];
#pragma unroll
        for (int nt = 0; nt < 2; ++nt)
            bfrag[nt] = WpF[((ks + 8) * 8 + wave * 2 + nt) * 64 + lane];
#pragma unroll
        for (int mt = 0; mt < 2; ++mt) {
            bf16x8 afrag = *reinterpret_cast<const bf16x8*>(
                &A[(mt * 16 + l15) * LDA + ks * 32 + quad * 8]);
#pragma unroll
            for (int nt = 0; nt < 2; ++nt)
                acc[mt][nt] = __builtin_amdgcn_mfma_f32_16x16x32_bf16(
                    afrag, bfrag[nt], acc[mt][nt], 0, 0, 0);
        }
    }

    // ---- epilogue ----
    const unsigned short* Hs = reinterpret_cast<const unsigned short*>(H);
#pragma unroll
    for (int mt = 0; mt < 2; ++mt)
#pragma unroll
        for (int r = 0; r < 4; ++r) {
            int m = mt * 16 + quad * 4 + r;
            float s = 0.f;
#pragma unroll
            for (int nt = 0; nt < 2; ++nt) {
                int n = (wave * 2 + nt) * 16 + l15;
                float h = acc[mt][nt][r] + b1v[nt] + bf2f(Hs[m * LDA + n]);
                h = fmaxf(h, 0.f);
                s += h * w2v[nt];
            }
            s += __shfl_xor(s, 1);
            s += __shfl_xor(s, 2);
            s += __shfl_xor(s, 4);
            s += __shfl_xor(s, 8);
            if (l15 == 0) red[wave][m] = s;
        }
    __syncthreads();

    if (tid < ET) {
        int eo = ebase + tid;
        if (eo < E) out[eo] = red[0][tid] + red[1][tid] + red[2][tid] + red[3][tid] + b2[0];
    }
}

// ===========================================================================
// Fallback (r1-proven single-kernel path) if ws too small.
// ===========================================================================
#define E_TILE 64
#define ROW_ELEMS 392

__global__ __launch_bounds__(256)
void decode_fallback(const float* __restrict__ zsrc,
                     const int* __restrict__ ei,
                     const bf16_t* __restrict__ Wp,
                     const float* __restrict__ b1,
                     const float* __restrict__ W2,
                     const float* __restrict__ b2,
                     float* __restrict__ out, int E) {
    __shared__ __align__(16) bf16_t Atile[E_TILE * ROW_ELEMS];
    __shared__ float red[2][E_TILE];
    const int tid = threadIdx.x;
    const int ebase = blockIdx.x * E_TILE;
#pragma unroll
    for (int i = 0; i < 8; ++i) {
        int half  = i * 16 + (tid >> 4);
        int m     = half >> 1;
        int which = half & 1;
        int e = ebase + m; if (e >= E) e = E - 1;
        int node = ei[which * E + e];
        int l16 = tid & 15;
        bf16_t* dst = &Atile[m * ROW_ELEMS + which * DIM + l16 * 8];
        const float4* src = reinterpret_cast<const float4*>(
            zsrc + (size_t)node * DIM + l16 * 8);
        float4 a = src[0], b = src[1];
        bf16x8 o;
        o[0]=(bf16_t)a.x; o[1]=(bf16_t)a.y; o[2]=(bf16_t)a.z; o[3]=(bf16_t)a.w;
        o[4]=(bf16_t)b.x; o[5]=(bf16_t)b.y; o[6]=(bf16_t)b.z; o[7]=(bf16_t)b.w;
        *reinterpret_cast<bf16x8*>(dst) = o;
    }
    __syncthreads();
#pragma unroll
    for (int i = 0; i < 4; ++i) {
        int chunk = i * 256 + tid;
        int m  = chunk >> 4;
        int cc = (chunk & 15) * 8;
        uint4 au = *reinterpret_cast<const uint4*>(&Atile[m * ROW_ELEMS + cc]);
        uint4 av = *reinterpret_cast<const uint4*>(&Atile[m * ROW_ELEMS + DIM + cc]);
        bf16x8 d;
        d[0]=(bf16_t)fabsf(bflo(au.x)-bflo(av.x));
        d[1]=(bf16_t)fabsf(bfhi(au.x)-bfhi(av.x));
        d[2]=(bf16_t)fabsf(bflo(au.y)-bflo(av.y));
        d[3]=(bf16_t)fabsf(bfhi(au.y)-bfhi(av.y));
        d[4]=(bf16_t)fabsf(bflo(au.z)-bflo(av.z));
        d[5]=(bf16_t)fabsf(bfhi(au.z)-bfhi(av.z));
        d[6]=(bf16_t)fabsf(bflo(au.w)-bflo(av.w));
        d[7]=(bf16_t)fabsf(bfhi(au.w)-bfhi(av.w));
        *reinterpret_cast<bf16x8*>(&Atile[m * ROW_ELEMS + 2 * DIM + cc]) = d;
    }
    __syncthreads();
    const int wave = tid >> 6, lane = tid & 63;
    const int wm = wave >> 1, wn = wave & 1;
    const int l15 = lane & 15, quad = lane >> 4;
    floatx4 acc[2][4];
#pragma unroll
    for (int mt = 0; mt < 2; ++mt)
#pragma unroll
        for (int nt = 0; nt < 4; ++nt) acc[mt][nt] = (floatx4)0.0f;
    float b1v[4], w2v[4];
#pragma unroll
    for (int nt = 0; nt < 4; ++nt) {
        int n = (wn * 4 + nt) * 16 + l15;
        b1v[nt] = b1[n];
        w2v[nt] = W2[n];
    }
    const bf16x8* WpF = reinterpret_cast<const bf16x8*>(Wp);
#pragma unroll
    for (int ks = 0; ks < N_KSTEP; ++ks) {
        bf16x8 bfrag[4];
#pragma unroll
        for (int nt = 0; nt < 4; ++nt)
            bfrag[nt] = WpF[(ks * N_NTILE + wn * 4 + nt) * 64 + lane];
#pragma unroll
        for (int mt = 0; mt < 2; ++mt) {
            int m = wm * 32 + mt * 16 + l15;
            bf16x8 afrag = *reinterpret_cast<const bf16x8*>(
                &Atile[m * ROW_ELEMS + ks * 32 + quad * 8]);
#pragma unroll
            for (int nt = 0; nt < 4; ++nt)
                acc[mt][nt] = __builtin_amdgcn_mfma_f32_16x16x32_bf16(
                    afrag, bfrag[nt], acc[mt][nt], 0, 0, 0);
        }
    }
    float partial[2][4];
#pragma unroll
    for (int mt = 0; mt < 2; ++mt)
#pragma unroll
        for (int r = 0; r < 4; ++r) {
            float s = 0.f;
#pragma unroll
            for (int nt = 0; nt < 4; ++nt) {
                float h = acc[mt][nt][r] + b1v[nt];
                h = fmaxf(h, 0.f);
                s += h * w2v[nt];
            }
            s += __shfl_xor(s, 1);
            s += __shfl_xor(s, 2);
            s += __shfl_xor(s, 4);
            s += __shfl_xor(s, 8);
            partial[mt][r] = s;
        }
    if (l15 == 0) {
#pragma unroll
        for (int mt = 0; mt < 2; ++mt)
#pragma unroll
            for (int r = 0; r < 4; ++r) {
                int m = wm * 32 + mt * 16 + quad * 4 + r;
                red[wn][m] = partial[mt][r];
            }
    }
    __syncthreads();
    if (tid < E_TILE) {
        int e = ebase + tid;
        if (e < E) out[e] = red[0][tid] + red[1][tid] + b2[0];
    }
}

// ===========================================================================
extern "C" void kernel_launch(void* const* d_in, const int* in_sizes, int n_in,
                              void* d_out, int out_size, void* d_ws, size_t ws_size,
                              hipStream_t stream) {
    const float* z  = (const float*)d_in[0];
    const int*   ei = (const int*)d_in[1];
    const float* W1 = (const float*)d_in[2];
    const float* b1 = (const float*)d_in[3];
    const float* W2 = (const float*)d_in[4];
    const float* b2 = (const float*)d_in[5];
    float* out = (float*)d_out;

    const int E  = in_sizes[1] / 2;
    const int Nn = in_sizes[0] / DIM;

    const size_t wp_bytes = (size_t)N_KSTEP * N_NTILE * 64 * 16;     // 96 KB
    const size_t u_bytes  = (size_t)Nn * 256 * sizeof(bf16_t);       // 51.2 MB
    const size_t pb_bytes = (size_t)Nn * DIM * sizeof(bf16_t);       // 25.6 MB

    const int packblk = (N_KSTEP * N_NTILE * 64 + 255) / 256;

    bf16_t* wp = (bf16_t*)d_ws;
    hipLaunchKernelGGL(pack_w1_kernel, dim3(packblk), dim3(256), 0, stream, W1, wp);

    if (ws_size >= wp_bytes + u_bytes + pb_bytes) {
        bf16_t* U   = (bf16_t*)((char*)d_ws + wp_bytes);
        bf16_t* Pbv = (bf16_t*)((char*)d_ws + wp_bytes + u_bytes);
        const int nblk = (Nn + NB_TILE - 1) / NB_TILE;
        hipLaunchKernelGGL(precompute_kernel, dim3(nblk), dim3(256), 0, stream,
                           z, wp, U, Pbv, Nn);
        const int eblocks = (E + ET - 1) / ET;
        hipLaunchKernelGGL(edge_kernel, dim3(eblocks), dim3(256), 0, stream,
                           U, Pbv, wp, ei, b1, W2, b2, out, E);
    } else {
        const int eblocks = (E + E_TILE - 1) / E_TILE;
        hipLaunchKernelGGL(decode_fallback, dim3(eblocks), dim3(256), 0, stream,
                           z, ei, wp, b1, W2, b2, out, E);
    }
}

// Round 5
// 186.925 us; speedup vs baseline: 1.6984x; 1.6984x over previous
//
#include <hip/hip_runtime.h>
#include <hip/hip_bf16.h>
#include <cstdint>

// ---------------------------------------------------------------------------
// MLPDecoder: logit[e] = relu([zu, zv, |zu-zv|] @ W1 + b1) @ W2 + b2
// Round-5 = Round-4 with the spill fixed:
//   r4's __launch_bounds__(256,8) forced VGPR<=64 -> compiler spilled the
//   gather staging to scratch (WRITE_SIZE 2MB -> 440MB, dur 92 -> 212us).
//   (256,4) caps at 128 VGPR: no spill; LDS 17.9KB still allows up to
//   8 blocks/CU if VGPR<=64.
//   Structure: feat@W1 = zu@W1a + zv@W1b + |zu-zv|@W1c
//   K0: pack W1 -> MFMA B-frag order (bf16)
//   K1: precompute U[node]=[bf16(z)|z@W1a] (512B rows), Pbv[node]=z@W1b.
//   K2: edge kernel, ET=32, 8 thr/edge; u-gather one 512B region,
//       v-gather 256B+256B; K=128 MFMA for |zu-zv|@W1c; epilogue fuses
//       +Pa+Pb+b1, relu, dot W2.
// ---------------------------------------------------------------------------

typedef __bf16 bf16_t;
typedef __bf16 bf16x8 __attribute__((ext_vector_type(8)));
typedef float  floatx4 __attribute__((ext_vector_type(4)));

#define DIM 128
#define LDA 136              // rows 272B; 2-way bank alias only (free)
#define LDP 264
#define NB_TILE 64
#define ET 32                // edges per block (kernel B)
#define N_KSTEP 12
#define N_NTILE 8

__device__ inline float bflo(unsigned w) { return __uint_as_float(w << 16); }
__device__ inline float bfhi(unsigned w) { return __uint_as_float(w & 0xffff0000u); }
__device__ inline float bf2f(unsigned short u) { return __uint_as_float(((unsigned)u) << 16); }

// ===========================================================================
// K0: pack W1 [384,128] f32 -> bf16 MFMA B-frag order.
// ===========================================================================
__global__ void pack_w1_kernel(const float* __restrict__ W1, bf16_t* __restrict__ Wp) {
    int f = blockIdx.x * 256 + threadIdx.x;
    if (f >= N_KSTEP * N_NTILE * 64) return;
    int lane = f & 63;
    int nt   = (f >> 6) & 7;
    int ks   = f >> 9;
    int n  = nt * 16 + (lane & 15);
    int k0 = ks * 32 + (lane >> 4) * 8;
    bf16x8 o;
#pragma unroll
    for (int j = 0; j < 8; ++j) o[j] = (bf16_t)W1[(k0 + j) * DIM + n];
    reinterpret_cast<bf16x8*>(Wp)[f] = o;
}

// ===========================================================================
// K1: U[node] = [bf16(z[node]) | Pa[node]],  Pbv[node] = Pb[node]
// ===========================================================================
__global__ __launch_bounds__(256)
void precompute_kernel(const float* __restrict__ z,
                       const bf16_t* __restrict__ Wp,
                       bf16_t* __restrict__ U,
                       bf16_t* __restrict__ Pbv,
                       int Nn) {
    __shared__ __align__(16) bf16_t A[NB_TILE * LDA];
    __shared__ __align__(16) bf16_t Pst[NB_TILE * LDP];
    const int tid = threadIdx.x;
    const int node0 = (int)blockIdx.x * NB_TILE;

#pragma unroll
    for (int i = 0; i < 4; ++i) {
        int t = i * 256 + tid;
        int m = t >> 4, c = (t & 15) * 8;
        int node = node0 + m;
        int nc = node < Nn ? node : Nn - 1;
        const float4* src = reinterpret_cast<const float4*>(z + (size_t)nc * DIM + c);
        float4 a = src[0], b = src[1];
        bf16x8 o;
        o[0]=(bf16_t)a.x; o[1]=(bf16_t)a.y; o[2]=(bf16_t)a.z; o[3]=(bf16_t)a.w;
        o[4]=(bf16_t)b.x; o[5]=(bf16_t)b.y; o[6]=(bf16_t)b.z; o[7]=(bf16_t)b.w;
        *reinterpret_cast<bf16x8*>(&A[m * LDA + c]) = o;
    }
    __syncthreads();

    const int wave = tid >> 6, lane = tid & 63;
    const int l15 = lane & 15, quad = lane >> 4;
    const bf16x8* WpF = reinterpret_cast<const bf16x8*>(Wp);

    floatx4 acc[4][4];
#pragma unroll
    for (int mt = 0; mt < 4; ++mt)
#pragma unroll
        for (int nt = 0; nt < 4; ++nt) acc[mt][nt] = (floatx4)0.0f;

#pragma unroll
    for (int ks = 0; ks < 4; ++ks) {
        bf16x8 bfrag[4];
#pragma unroll
        for (int nt = 0; nt < 4; ++nt) {
            int f = (ks + (wave >> 1) * 4) * 8 + (wave & 1) * 4 + nt;
            bfrag[nt] = WpF[f * 64 + lane];
        }
#pragma unroll
        for (int mt = 0; mt < 4; ++mt) {
            bf16x8 afrag = *reinterpret_cast<const bf16x8*>(
                &A[(mt * 16 + l15) * LDA + ks * 32 + quad * 8]);
#pragma unroll
            for (int nt = 0; nt < 4; ++nt)
                acc[mt][nt] = __builtin_amdgcn_mfma_f32_16x16x32_bf16(
                    afrag, bfrag[nt], acc[mt][nt], 0, 0, 0);
        }
    }

#pragma unroll
    for (int mt = 0; mt < 4; ++mt)
#pragma unroll
        for (int r = 0; r < 4; ++r) {
            int row = mt * 16 + quad * 4 + r;
#pragma unroll
            for (int nt = 0; nt < 4; ++nt) {
                int col = wave * 64 + nt * 16 + l15;
                Pst[row * LDP + col] = (bf16_t)acc[mt][nt][r];
            }
        }
    __syncthreads();

#pragma unroll
    for (int i = 0; i < 4; ++i) {
        int t = i * 256 + tid;
        int m = t >> 4, c = (t & 15) * 8;
        int node = node0 + m;
        if (node < Nn) {
            uint4 zb4 = *reinterpret_cast<const uint4*>(&A[m * LDA + c]);
            uint4 pa4 = *reinterpret_cast<const uint4*>(&Pst[m * LDP + c]);
            uint4 pb4 = *reinterpret_cast<const uint4*>(&Pst[m * LDP + DIM + c]);
            *reinterpret_cast<uint4*>(U + (size_t)node * 256 + c)        = zb4;
            *reinterpret_cast<uint4*>(U + (size_t)node * 256 + DIM + c)  = pa4;
            *reinterpret_cast<uint4*>(Pbv + (size_t)node * DIM + c)      = pb4;
        }
    }
}

// ===========================================================================
// K2: edge kernel, 32 edges/block, 8 threads/edge.
// __launch_bounds__(256,4): VGPR cap 128 -> no spill (r4's (256,8) spilled).
// ===========================================================================
__global__ __launch_bounds__(256, 4)
void edge_kernel(const bf16_t* __restrict__ U,
                 const bf16_t* __restrict__ Pbv,
                 const bf16_t* __restrict__ Wp,
                 const int* __restrict__ ei,
                 const float* __restrict__ b1,
                 const float* __restrict__ W2,
                 const float* __restrict__ b2,
                 float* __restrict__ out, int E) {
    __shared__ __align__(16) bf16_t A[ET * LDA];   // 8704 B
    __shared__ __align__(16) bf16_t H[ET * LDA];   // 8704 B
    __shared__ float red[4][ET];                   // 512 B

    const int tid = threadIdx.x;
    const int ebase = (int)blockIdx.x * ET;
    const int el  = tid >> 3;      // edge 0..31
    const int sub = tid & 7;       // chunk 0..7

    int e = ebase + el; if (e >= E) e = E - 1;
    int u = ei[e], v = ei[E + e];

    const uint4* pu = reinterpret_cast<const uint4*>(U + (size_t)u * 256 + sub * 32);
    const uint4* pv = (sub < 4)
        ? reinterpret_cast<const uint4*>(U + (size_t)v * 256 + sub * 32)
        : reinterpret_cast<const uint4*>(Pbv + (size_t)v * DIM + (sub - 4) * 32);
    uint4 gu[4], gv[4];
#pragma unroll
    for (int j = 0; j < 4; ++j) gu[j] = pu[j];
#pragma unroll
    for (int j = 0; j < 4; ++j) gv[j] = pv[j];

    const int wave = tid >> 6, lane = tid & 63;
    const int l15 = lane & 15, quad = lane >> 4;

    float b1v[2], w2v[2];
#pragma unroll
    for (int nt = 0; nt < 2; ++nt) {
        int n = (wave * 2 + nt) * 16 + l15;
        b1v[nt] = b1[n];
        w2v[nt] = W2[n];
    }

    if (sub < 4) {
        bf16_t* dst = &A[el * LDA + sub * 32];
#pragma unroll
        for (int j = 0; j < 4; ++j) {
            uint4 a = gu[j], b = gv[j];
            bf16x8 d;
            d[0]=(bf16_t)fabsf(bflo(a.x)-bflo(b.x));
            d[1]=(bf16_t)fabsf(bfhi(a.x)-bfhi(b.x));
            d[2]=(bf16_t)fabsf(bflo(a.y)-bflo(b.y));
            d[3]=(bf16_t)fabsf(bfhi(a.y)-bfhi(b.y));
            d[4]=(bf16_t)fabsf(bflo(a.z)-bflo(b.z));
            d[5]=(bf16_t)fabsf(bfhi(a.z)-bfhi(b.z));
            d[6]=(bf16_t)fabsf(bflo(a.w)-bflo(b.w));
            d[7]=(bf16_t)fabsf(bfhi(a.w)-bfhi(b.w));
            *reinterpret_cast<bf16x8*>(dst + j * 8) = d;
        }
    } else {
        bf16_t* dst = &H[el * LDA + (sub - 4) * 32];
#pragma unroll
        for (int j = 0; j < 4; ++j) {
            uint4 a = gu[j], b = gv[j];
            bf16x8 h;
            h[0]=(bf16_t)(bflo(a.x)+bflo(b.x));
            h[1]=(bf16_t)(bfhi(a.x)+bfhi(b.x));
            h[2]=(bf16_t)(bflo(a.y)+bflo(b.y));
            h[3]=(bf16_t)(bfhi(a.y)+bfhi(b.y));
            h[4]=(bf16_t)(bflo(a.z)+bflo(b.z));
            h[5]=(bf16_t)(bfhi(a.z)+bfhi(b.z));
            h[6]=(bf16_t)(bflo(a.w)+bflo(b.w));
            h[7]=(bf16_t)(bfhi(a.w)+bfhi(b.w));
            *reinterpret_cast<bf16x8*>(dst + j * 8) = h;
        }
    }
    __syncthreads();

    floatx4 acc[2][2];
#pragma unroll
    for (int mt = 0; mt < 2; ++mt)
#pragma unroll
        for (int nt = 0; nt < 2; ++nt) acc[mt][nt] = (floatx4)0.0f;

    const bf16x8* WpF = reinterpret_cast<const bf16x8*>(Wp);
#pragma unroll
    for (int ks = 0; ks < 4; ++ks) {
        bf16x8 bfrag[2];
#pragma unroll
        for (int nt = 0; nt < 2; ++nt)
            bfrag[nt] = WpF[((ks + 8) * 8 + wave * 2 + nt) * 64 + lane];
#pragma unroll
        for (int mt = 0; mt < 2; ++mt) {
            bf16x8 afrag = *reinterpret_cast<const bf16x8*>(
                &A[(mt * 16 + l15) * LDA + ks * 32 + quad * 8]);
#pragma unroll
            for (int nt = 0; nt < 2; ++nt)
                acc[mt][nt] = __builtin_amdgcn_mfma_f32_16x16x32_bf16(
                    afrag, bfrag[nt], acc[mt][nt], 0, 0, 0);
        }
    }

    const unsigned short* Hs = reinterpret_cast<const unsigned short*>(H);
#pragma unroll
    for (int mt = 0; mt < 2; ++mt)
#pragma unroll
        for (int r = 0; r < 4; ++r) {
            int m = mt * 16 + quad * 4 + r;
            float s = 0.f;
#pragma unroll
            for (int nt = 0; nt < 2; ++nt) {
                int n = (wave * 2 + nt) * 16 + l15;
                float h = acc[mt][nt][r] + b1v[nt] + bf2f(Hs[m * LDA + n]);
                h = fmaxf(h, 0.f);
                s += h * w2v[nt];
            }
            s += __shfl_xor(s, 1);
            s += __shfl_xor(s, 2);
            s += __shfl_xor(s, 4);
            s += __shfl_xor(s, 8);
            if (l15 == 0) red[wave][m] = s;
        }
    __syncthreads();

    if (tid < ET) {
        int eo = ebase + tid;
        if (eo < E) out[eo] = red[0][tid] + red[1][tid] + red[2][tid] + red[3][tid] + b2[0];
    }
}

// ===========================================================================
// Fallback (r1-proven single-kernel path) if ws too small.
// ===========================================================================
#define E_TILE 64
#define ROW_ELEMS 392

__global__ __launch_bounds__(256)
void decode_fallback(const float* __restrict__ zsrc,
                     const int* __restrict__ ei,
                     const bf16_t* __restrict__ Wp,
                     const float* __restrict__ b1,
                     const float* __restrict__ W2,
                     const float* __restrict__ b2,
                     float* __restrict__ out, int E) {
    __shared__ __align__(16) bf16_t Atile[E_TILE * ROW_ELEMS];
    __shared__ float red[2][E_TILE];
    const int tid = threadIdx.x;
    const int ebase = blockIdx.x * E_TILE;
#pragma unroll
    for (int i = 0; i < 8; ++i) {
        int half  = i * 16 + (tid >> 4);
        int m     = half >> 1;
        int which = half & 1;
        int e = ebase + m; if (e >= E) e = E - 1;
        int node = ei[which * E + e];
        int l16 = tid & 15;
        bf16_t* dst = &Atile[m * ROW_ELEMS + which * DIM + l16 * 8];
        const float4* src = reinterpret_cast<const float4*>(
            zsrc + (size_t)node * DIM + l16 * 8);
        float4 a = src[0], b = src[1];
        bf16x8 o;
        o[0]=(bf16_t)a.x; o[1]=(bf16_t)a.y; o[2]=(bf16_t)a.z; o[3]=(bf16_t)a.w;
        o[4]=(bf16_t)b.x; o[5]=(bf16_t)b.y; o[6]=(bf16_t)b.z; o[7]=(bf16_t)b.w;
        *reinterpret_cast<bf16x8*>(dst) = o;
    }
    __syncthreads();
#pragma unroll
    for (int i = 0; i < 4; ++i) {
        int chunk = i * 256 + tid;
        int m  = chunk >> 4;
        int cc = (chunk & 15) * 8;
        uint4 au = *reinterpret_cast<const uint4*>(&Atile[m * ROW_ELEMS + cc]);
        uint4 av = *reinterpret_cast<const uint4*>(&Atile[m * ROW_ELEMS + DIM + cc]);
        bf16x8 d;
        d[0]=(bf16_t)fabsf(bflo(au.x)-bflo(av.x));
        d[1]=(bf16_t)fabsf(bfhi(au.x)-bfhi(av.x));
        d[2]=(bf16_t)fabsf(bflo(au.y)-bflo(av.y));
        d[3]=(bf16_t)fabsf(bfhi(au.y)-bfhi(av.y));
        d[4]=(bf16_t)fabsf(bflo(au.z)-bflo(av.z));
        d[5]=(bf16_t)fabsf(bfhi(au.z)-bfhi(av.z));
        d[6]=(bf16_t)fabsf(bflo(au.w)-bflo(av.w));
        d[7]=(bf16_t)fabsf(bfhi(au.w)-bfhi(av.w));
        *reinterpret_cast<bf16x8*>(&Atile[m * ROW_ELEMS + 2 * DIM + cc]) = d;
    }
    __syncthreads();
    const int wave = tid >> 6, lane = tid & 63;
    const int wm = wave >> 1, wn = wave & 1;
    const int l15 = lane & 15, quad = lane >> 4;
    floatx4 acc[2][4];
#pragma unroll
    for (int mt = 0; mt < 2; ++mt)
#pragma unroll
        for (int nt = 0; nt < 4; ++nt) acc[mt][nt] = (floatx4)0.0f;
    float b1v[4], w2v[4];
#pragma unroll
    for (int nt = 0; nt < 4; ++nt) {
        int n = (wn * 4 + nt) * 16 + l15;
        b1v[nt] = b1[n];
        w2v[nt] = W2[n];
    }
    const bf16x8* WpF = reinterpret_cast<const bf16x8*>(Wp);
#pragma unroll
    for (int ks = 0; ks < N_KSTEP; ++ks) {
        bf16x8 bfrag[4];
#pragma unroll
        for (int nt = 0; nt < 4; ++nt)
            bfrag[nt] = WpF[(ks * N_NTILE + wn * 4 + nt) * 64 + lane];
#pragma unroll
        for (int mt = 0; mt < 2; ++mt) {
            int m = wm * 32 + mt * 16 + l15;
            bf16x8 afrag = *reinterpret_cast<const bf16x8*>(
                &Atile[m * ROW_ELEMS + ks * 32 + quad * 8]);
#pragma unroll
            for (int nt = 0; nt < 4; ++nt)
                acc[mt][nt] = __builtin_amdgcn_mfma_f32_16x16x32_bf16(
                    afrag, bfrag[nt], acc[mt][nt], 0, 0, 0);
        }
    }
    float partial[2][4];
#pragma unroll
    for (int mt = 0; mt < 2; ++mt)
#pragma unroll
        for (int r = 0; r < 4; ++r) {
            float s = 0.f;
#pragma unroll
            for (int nt = 0; nt < 4; ++nt) {
                float h = acc[mt][nt][r] + b1v[nt];
                h = fmaxf(h, 0.f);
                s += h * w2v[nt];
            }
            s += __shfl_xor(s, 1);
            s += __shfl_xor(s, 2);
            s += __shfl_xor(s, 4);
            s += __shfl_xor(s, 8);
            partial[mt][r] = s;
        }
    if (l15 == 0) {
#pragma unroll
        for (int mt = 0; mt < 2; ++mt)
#pragma unroll
            for (int r = 0; r < 4; ++r) {
                int m = wm * 32 + mt * 16 + quad * 4 + r;
                red[wn][m] = partial[mt][r];
            }
    }
    __syncthreads();
    if (tid < E_TILE) {
        int e = ebase + tid;
        if (e < E) out[e] = red[0][tid] + red[1][tid] + b2[0];
    }
}

// ===========================================================================
extern "C" void kernel_launch(void* const* d_in, const int* in_sizes, int n_in,
                              void* d_out, int out_size, void* d_ws, size_t ws_size,
                              hipStream_t stream) {
    const float* z  = (const float*)d_in[0];
    const int*   ei = (const int*)d_in[1];
    const float* W1 = (const float*)d_in[2];
    const float* b1 = (const float*)d_in[3];
    const float* W2 = (const float*)d_in[4];
    const float* b2 = (const float*)d_in[5];
    float* out = (float*)d_out;

    const int E  = in_sizes[1] / 2;
    const int Nn = in_sizes[0] / DIM;

    const size_t wp_bytes = (size_t)N_KSTEP * N_NTILE * 64 * 16;     // 96 KB
    const size_t u_bytes  = (size_t)Nn * 256 * sizeof(bf16_t);       // 51.2 MB
    const size_t pb_bytes = (size_t)Nn * DIM * sizeof(bf16_t);       // 25.6 MB

    const int packblk = (N_KSTEP * N_NTILE * 64 + 255) / 256;

    bf16_t* wp = (bf16_t*)d_ws;
    hipLaunchKernelGGL(pack_w1_kernel, dim3(packblk), dim3(256), 0, stream, W1, wp);

    if (ws_size >= wp_bytes + u_bytes + pb_bytes) {
        bf16_t* U   = (bf16_t*)((char*)d_ws + wp_bytes);
        bf16_t* Pbv = (bf16_t*)((char*)d_ws + wp_bytes + u_bytes);
        const int nblk = (Nn + NB_TILE - 1) / NB_TILE;
        hipLaunchKernelGGL(precompute_kernel, dim3(nblk), dim3(256), 0, stream,
                           z, wp, U, Pbv, Nn);
        const int eblocks = (E + ET - 1) / ET;
        hipLaunchKernelGGL(edge_kernel, dim3(eblocks), dim3(256), 0, stream,
                           U, Pbv, wp, ei, b1, W2, b2, out, E);
    } else {
        const int eblocks = (E + E_TILE - 1) / E_TILE;
        hipLaunchKernelGGL(decode_fallback, dim3(eblocks), dim3(256), 0, stream,
                           z, ei, wp, b1, W2, b2, out, E);
    }
}